// Round 2
// baseline (1907.179 us; speedup 1.0000x reference)
//
#include <hip/hip_runtime.h>
#include <hip/hip_bf16.h>

typedef __hip_bfloat16 bf16;

__device__ __forceinline__ float toF(bf16 v){ return __bfloat162float(v); }
__device__ __forceinline__ float toF(float v){ return v; }
__device__ __forceinline__ void storeT(bf16* p, float v){ *p = __float2bfloat16(v); }
__device__ __forceinline__ void storeT(float* p, float v){ *p = v; }

// ---------------------------------------------------------------------------
// Generic tiled GEMM: C[M,Nc] = A[M,K] @ B[K,Nc] (+bias). fp32 accumulate.
// 64x64 tile, 256 threads, 4x4 microtile. M%64==0, Nc%64==0, K%16==0.
// A: fp32 or bf16 (templated). Weights/bias: fp32 (harness inputs).
// ---------------------------------------------------------------------------
template<typename AT, typename OT>
__global__ __launch_bounds__(256) void gemm_tiled(
    const AT* __restrict__ A, const float* __restrict__ Bw,
    const float* __restrict__ bias, OT* __restrict__ Co,
    int M, int K, int Nc) {
  __shared__ float As[16][68];
  __shared__ float Bs[16][68];
  const int tid = threadIdx.x;
  const int m0 = blockIdx.y * 64;
  const int n0 = blockIdx.x * 64;
  const int tx = tid & 15;
  const int ty = tid >> 4;
  const int liA_m = (tid * 4) >> 4;
  const int liA_k = (tid * 4) & 15;
  const int liB_k = (tid * 4) >> 6;
  const int liB_n = (tid * 4) & 63;
  float acc[4][4] = {};
  for (int ks = 0; ks < K; ks += 16) {
    const AT* ap = A + (size_t)(m0 + liA_m) * K + ks + liA_k;
#pragma unroll
    for (int j = 0; j < 4; j++) As[liA_k + j][liA_m] = toF(ap[j]);
    const float* bp = Bw + (size_t)(ks + liB_k) * Nc + n0 + liB_n;
#pragma unroll
    for (int j = 0; j < 4; j++) Bs[liB_k][liB_n + j] = bp[j];
    __syncthreads();
#pragma unroll
    for (int kk = 0; kk < 16; kk++) {
      float a[4], bb[4];
#pragma unroll
      for (int i = 0; i < 4; i++) a[i] = As[kk][ty * 4 + i];
#pragma unroll
      for (int j = 0; j < 4; j++) bb[j] = Bs[kk][tx * 4 + j];
#pragma unroll
      for (int i = 0; i < 4; i++)
#pragma unroll
        for (int j = 0; j < 4; j++) acc[i][j] += a[i] * bb[j];
    }
    __syncthreads();
  }
#pragma unroll
  for (int j = 0; j < 4; j++) {
    int ncol = n0 + tx * 4 + j;
    float bv = bias ? bias[ncol] : 0.0f;
#pragma unroll
    for (int i = 0; i < 4; i++) {
      int mrow = m0 + ty * 4 + i;
      storeT(&Co[(size_t)mrow * Nc + ncol], acc[i][j] + bv);
    }
  }
}

// ---------------------------------------------------------------------------
// proj GEMM with fused A = concat(x1,x2) + lepe.  K=256, Nc=256 fixed.
// Output fp32 (d_out).
// ---------------------------------------------------------------------------
__global__ __launch_bounds__(256) void gemm_proj(
    const bf16* __restrict__ X1, const bf16* __restrict__ X2,
    const bf16* __restrict__ L2, const float* __restrict__ Bw,
    const float* __restrict__ bias, float* __restrict__ Co) {
  __shared__ float As[16][68];
  __shared__ float Bs[16][68];
  const int tid = threadIdx.x;
  const int m0 = blockIdx.y * 64;
  const int n0 = blockIdx.x * 64;
  const int tx = tid & 15;
  const int ty = tid >> 4;
  const int liA_m = (tid * 4) >> 4;
  const int liA_k = (tid * 4) & 15;
  const int liB_k = (tid * 4) >> 6;
  const int liB_n = (tid * 4) & 63;
  float acc[4][4] = {};
  for (int ks = 0; ks < 256; ks += 16) {
    const int mrow = m0 + liA_m;
#pragma unroll
    for (int j = 0; j < 4; j++) {
      int k = ks + liA_k + j;
      float v = (k < 128) ? toF(X1[(size_t)mrow * 128 + k])
                          : toF(X2[(size_t)mrow * 128 + (k - 128)]);
      v += toF(L2[(size_t)mrow * 256 + k]);
      As[liA_k + j][liA_m] = v;
    }
    const float* bp = Bw + (size_t)(ks + liB_k) * 256 + n0 + liB_n;
#pragma unroll
    for (int j = 0; j < 4; j++) Bs[liB_k][liB_n + j] = bp[j];
    __syncthreads();
#pragma unroll
    for (int kk = 0; kk < 16; kk++) {
      float a[4], bb[4];
#pragma unroll
      for (int i = 0; i < 4; i++) a[i] = As[kk][ty * 4 + i];
#pragma unroll
      for (int j = 0; j < 4; j++) bb[j] = Bs[kk][tx * 4 + j];
#pragma unroll
      for (int i = 0; i < 4; i++)
#pragma unroll
        for (int j = 0; j < 4; j++) acc[i][j] += a[i] * bb[j];
    }
    __syncthreads();
  }
#pragma unroll
  for (int j = 0; j < 4; j++) {
    int ncol = n0 + tx * 4 + j;
    float bv = bias[ncol];
#pragma unroll
    for (int i = 0; i < 4; i++) {
      int mrow = m0 + ty * 4 + i;
      Co[(size_t)mrow * 256 + ncol] = acc[i][j] + bv;
    }
  }
}

// ---------------------------------------------------------------------------
// Depthwise 3x3 SAME conv, NHWC, B=32,H=W=56,C=256. One thread per element.
// ---------------------------------------------------------------------------
__global__ __launch_bounds__(256) void dwconv_kernel(
    const bf16* __restrict__ in, const float* __restrict__ w,
    const float* __restrict__ bias, bf16* __restrict__ out) {
  const size_t idx = (size_t)blockIdx.x * 256 + threadIdx.x;
  const int c = (int)(idx & 255);
  const int sp = (int)(idx >> 8);
  const int xx = sp % 56;
  const int yb = sp / 56;
  const int yy = yb % 56;
  const int b  = yb / 56;
  float acc = bias[c];
#pragma unroll
  for (int dy = 0; dy < 3; dy++) {
    int y = yy + dy - 1;
    if ((unsigned)y >= 56u) continue;
#pragma unroll
    for (int dx = 0; dx < 3; dx++) {
      int x = xx + dx - 1;
      if ((unsigned)x >= 56u) continue;
      acc += toF(in[((size_t)((b * 56 + y) * 56 + x)) * 256 + c]) *
             w[(dy * 3 + dx) * 256 + c];
    }
  }
  out[idx] = __float2bfloat16(acc);
}

// ---------------------------------------------------------------------------
// sr conv: 4x4 stride 4 VALID. x fp32 in, staged bf16 in LDS.
// Output [B*196, 256] fp32 (pre-LN). Block = 8 tokens x 256 couts.
// ---------------------------------------------------------------------------
__global__ __launch_bounds__(256) void srconv_kernel(
    const float* __restrict__ x, const float* __restrict__ w,
    const float* __restrict__ bias, float* __restrict__ out) {
  __shared__ bf16 patch[8][2048];
  const int tid = threadIdx.x;
  const int tok0 = blockIdx.x * 8;
  const int cout = tid;
  float acc[8] = {0, 0, 0, 0, 0, 0, 0, 0};
  for (int kc = 0; kc < 4096; kc += 2048) {
    __syncthreads();
    for (int i = tid; i < 8 * 2048; i += 256) {
      int t = i >> 11;
      int k = i & 2047;
      int kg = kc + k;
      int tok = tok0 + t;
      int b = tok / 196;
      int p = tok - b * 196;
      int oy = p / 14, ox = p - (p / 14) * 14;
      int kp = kg >> 8;
      int c = kg & 255;
      int ky = kp >> 2, kx = kp & 3;
      patch[t][k] = __float2bfloat16(
          x[((size_t)((b * 56 + oy * 4 + ky) * 56 + ox * 4 + kx)) * 256 + c]);
    }
    __syncthreads();
#pragma unroll 4
    for (int k = 0; k < 2048; k++) {
      float wv = w[(size_t)(kc + k) * 256 + cout];
#pragma unroll
      for (int t = 0; t < 8; t++) acc[t] += wv * toF(patch[t][k]);
    }
  }
  float bv = bias[cout];
#pragma unroll
  for (int t = 0; t < 8; t++) {
    int tok = tok0 + t;
    out[(size_t)tok * 256 + cout] = acc[t] + bv;
  }
}

// ---------------------------------------------------------------------------
// LayerNorm (over C=256) + exact GELU. One block per token. In-place safe.
// ---------------------------------------------------------------------------
__global__ __launch_bounds__(256) void ln_gelu_kernel(
    const float* __restrict__ in, const float* __restrict__ g,
    const float* __restrict__ bb, float* __restrict__ out) {
  const int tok = blockIdx.x;
  const int tid = threadIdx.x;
  float v = in[(size_t)tok * 256 + tid];
  float s = v, s2 = v * v;
#pragma unroll
  for (int o = 32; o > 0; o >>= 1) {
    s += __shfl_down(s, o, 64);
    s2 += __shfl_down(s2, o, 64);
  }
  __shared__ float rs[4], rs2[4];
  int wid = tid >> 6, lane = tid & 63;
  if (lane == 0) { rs[wid] = s; rs2[wid] = s2; }
  __syncthreads();
  float tot = rs[0] + rs[1] + rs[2] + rs[3];
  float tot2 = rs2[0] + rs2[1] + rs2[2] + rs2[3];
  float mean = tot * (1.0f / 256.0f);
  float var = tot2 * (1.0f / 256.0f) - mean * mean;
  float y = (v - mean) * rsqrtf(var + 1e-5f) * g[tid] + bb[tid];
  out[(size_t)tok * 256 + tid] = 0.5f * y * (1.0f + erff(y * 0.70710678118654752f));
}

// ---------------------------------------------------------------------------
// attn1: global attention, kv from 196 downsampled tokens. One thread = 1 query.
// grid (13 qchunks, h2=4, B=32), block 256. K/V staged fp32 in LDS.
// ---------------------------------------------------------------------------
__global__ __launch_bounds__(256) void attn1_kernel(
    const bf16* __restrict__ Q, const float* __restrict__ KV,
    bf16* __restrict__ O) {
  __shared__ float sk[196 * 32];
  __shared__ float sv[196 * 32];
  const int b = blockIdx.z, h = blockIdx.y, chunk = blockIdx.x;
  const int tid = threadIdx.x;
  for (int i = tid; i < 196 * 32; i += 256) {
    int m = i >> 5, dd = i & 31;
    const float* kvp = KV + ((size_t)(b * 196 + m)) * 256 + h * 32 + dd;
    sk[i] = kvp[0];
    sv[i] = kvp[128];
  }
  __syncthreads();
  const int qrow = chunk * 256 + tid;
  if (qrow >= 3136) return;
  float q[32];
  const bf16* qp = Q + ((size_t)(b * 3136 + qrow)) * 128 + h * 32;
#pragma unroll
  for (int dd = 0; dd < 32; dd++) q[dd] = toF(qp[dd]);
  const float scale = 0.17677669529663687f;  // 32^-0.5
  float mx = -1e30f;
  for (int m = 0; m < 196; m++) {
    const float* kp = sk + m * 32;
    float s = 0.f;
#pragma unroll
    for (int dd = 0; dd < 32; dd++) s += q[dd] * kp[dd];
    mx = fmaxf(mx, s * scale);
  }
  float l = 0.f;
  float acc[32] = {};
  for (int m = 0; m < 196; m++) {
    const float* kp = sk + m * 32;
    float s = 0.f;
#pragma unroll
    for (int dd = 0; dd < 32; dd++) s += q[dd] * kp[dd];
    float p = __expf(s * scale - mx);
    l += p;
    const float* vp = sv + m * 32;
#pragma unroll
    for (int dd = 0; dd < 32; dd++) acc[dd] += p * vp[dd];
  }
  float inv = 1.0f / l;
  bf16* op = O + ((size_t)(b * 3136 + qrow)) * 128 + h * 32;
#pragma unroll
  for (int dd = 0; dd < 32; dd++) op[dd] = __float2bfloat16(acc[dd] * inv);
}

// ---------------------------------------------------------------------------
// attn2: 7x7 window attention. One block (64 thr) per (window, h, b); 49 queries.
// ---------------------------------------------------------------------------
__global__ __launch_bounds__(64) void attn2_kernel(
    const bf16* __restrict__ Q2, const bf16* __restrict__ KV2,
    bf16* __restrict__ O) {
  __shared__ float sk[49 * 32];
  __shared__ float sv[49 * 32];
  const int b = blockIdx.z, h = blockIdx.y, wi = blockIdx.x;
  const int wy = wi >> 3, wx = wi & 7;
  const int tid = threadIdx.x;
  for (int i = tid; i < 49 * 32; i += 64) {
    int m = i >> 5, dd = i & 31;
    int iy = m / 7, ix = m - (m / 7) * 7;
    int n = (wy * 7 + iy) * 56 + wx * 7 + ix;
    const bf16* kvp = KV2 + ((size_t)(b * 3136 + n)) * 256 + h * 32 + dd;
    sk[i] = toF(kvp[0]);
    sv[i] = toF(kvp[128]);
  }
  __syncthreads();
  if (tid >= 49) return;
  const int iy = tid / 7, ix = tid - (tid / 7) * 7;
  const int n = (wy * 7 + iy) * 56 + wx * 7 + ix;
  float q[32];
  const bf16* qp = Q2 + ((size_t)(b * 3136 + n)) * 128 + h * 32;
#pragma unroll
  for (int dd = 0; dd < 32; dd++) q[dd] = toF(qp[dd]);
  const float scale = 0.17677669529663687f;
  float mx = -1e30f;
  for (int m = 0; m < 49; m++) {
    const float* kp = sk + m * 32;
    float s = 0.f;
#pragma unroll
    for (int dd = 0; dd < 32; dd++) s += q[dd] * kp[dd];
    mx = fmaxf(mx, s * scale);
  }
  float l = 0.f;
  float acc[32] = {};
  for (int m = 0; m < 49; m++) {
    const float* kp = sk + m * 32;
    float s = 0.f;
#pragma unroll
    for (int dd = 0; dd < 32; dd++) s += q[dd] * kp[dd];
    float p = __expf(s * scale - mx);
    l += p;
    const float* vp = sv + m * 32;
#pragma unroll
    for (int dd = 0; dd < 32; dd++) acc[dd] += p * vp[dd];
  }
  float inv = 1.0f / l;
  bf16* op = O + ((size_t)(b * 3136 + n)) * 128 + h * 32;
#pragma unroll
  for (int dd = 0; dd < 32; dd++) op[dd] = __float2bfloat16(acc[dd] * inv);
}

// ---------------------------------------------------------------------------
extern "C" void kernel_launch(void* const* d_in, const int* in_sizes, int n_in,
                              void* d_out, int out_size, void* d_ws, size_t ws_size,
                              hipStream_t stream) {
  const float* x           = (const float*)d_in[0];
  const float* lepe_lin_w  = (const float*)d_in[1];
  const float* lepe_lin_b  = (const float*)d_in[2];
  const float* lepe_conv_w = (const float*)d_in[3];
  const float* lepe_conv_b = (const float*)d_in[4];
  const float* sr_w        = (const float*)d_in[5];
  const float* sr_b        = (const float*)d_in[6];
  const float* norm_g      = (const float*)d_in[7];
  const float* norm_b      = (const float*)d_in[8];
  const float* q1_w        = (const float*)d_in[9];
  const float* kv1_w       = (const float*)d_in[10];
  const float* q2_w        = (const float*)d_in[11];
  const float* kv2_w       = (const float*)d_in[12];
  const float* proj_w      = (const float*)d_in[13];
  const float* proj_b      = (const float*)d_in[14];
  float* out = (float*)d_out;

  // Workspace layout (lifetime-based reuse; max offset ~147 MiB):
  //  R0 [0, 51.4MB):  L1 (lepe_lin) -> KV2 -> {X1P fp32 @0, KV1 fp32 @8MB, X1 bf16 @16MB}
  //  R1 [51.4, 102.8MB): L2 (lepe, persists to proj)
  //  R2 [102.8, 128.5MB): Q2 -> Q1
  //  R3 [128.5, 154.2MB): X2
  char* ws = (char*)d_ws;
  const size_t szBNC = 100352ull * 256 * 2;   // 51,380,224
  const size_t szBNh = 100352ull * 128 * 2;   // 25,690,112
  bf16*  L1  = (bf16*)(ws);
  bf16*  KV2 = (bf16*)(ws);
  float* X1P = (float*)(ws);
  float* KV1 = (float*)(ws + (8u << 20));
  bf16*  X1  = (bf16*)(ws + (16u << 20));
  bf16*  L2  = (bf16*)(ws + szBNC);
  bf16*  Q2  = (bf16*)(ws + 2 * szBNC);
  bf16*  Q1  = Q2;
  bf16*  X2  = (bf16*)(ws + 2 * szBNC + szBNh);

  // 1. lepe linear, 2. depthwise conv
  gemm_tiled<float, bf16><<<dim3(4, 1568), 256, 0, stream>>>(
      x, lepe_lin_w, lepe_lin_b, L1, 100352, 256, 256);
  dwconv_kernel<<<dim3(100352), 256, 0, stream>>>(L1, lepe_conv_w, lepe_conv_b, L2);
  // 3-5. branch 2 (window attention)
  gemm_tiled<float, bf16><<<dim3(4, 1568), 256, 0, stream>>>(
      x, kv2_w, nullptr, KV2, 100352, 256, 256);
  gemm_tiled<float, bf16><<<dim3(2, 1568), 256, 0, stream>>>(
      x, q2_w, nullptr, Q2, 100352, 256, 128);
  attn2_kernel<<<dim3(64, 4, 32), 64, 0, stream>>>(Q2, KV2, X2);
  // 6-10. branch 1 (sr-downsampled global attention)
  gemm_tiled<float, bf16><<<dim3(2, 1568), 256, 0, stream>>>(
      x, q1_w, nullptr, Q1, 100352, 256, 128);
  srconv_kernel<<<dim3(784), 256, 0, stream>>>(x, sr_w, sr_b, X1P);
  ln_gelu_kernel<<<dim3(6272), 256, 0, stream>>>(X1P, norm_g, norm_b, X1P);
  gemm_tiled<float, float><<<dim3(4, 98), 256, 0, stream>>>(
      X1P, kv1_w, nullptr, KV1, 6272, 256, 256);
  attn1_kernel<<<dim3(13, 4, 32), 256, 0, stream>>>(Q1, KV1, X1);
  // 11. fused concat + lepe add + proj
  gemm_proj<<<dim3(4, 1568), 256, 0, stream>>>(X1, X2, L2, proj_w, proj_b, out);
}

// Round 3
// 904.576 us; speedup vs baseline: 2.1084x; 2.1084x over previous
//
#include <hip/hip_runtime.h>
#include <hip/hip_bf16.h>

typedef __hip_bfloat16 bf16;
typedef __attribute__((ext_vector_type(8))) short short8;
typedef __attribute__((ext_vector_type(4))) float floatx4;

__device__ __forceinline__ float toF(bf16 v){ return __bfloat162float(v); }
__device__ __forceinline__ float b2f(unsigned short u){
  return __uint_as_float(((unsigned int)u) << 16);
}
__device__ __forceinline__ unsigned short f2bu(float f){
  bf16 h = __float2bfloat16(f);
  return *(unsigned short*)&h;
}
__device__ __forceinline__ void storeT(bf16* p, float v){ *p = __float2bfloat16(v); }
__device__ __forceinline__ void storeT(float* p, float v){ *p = v; }

// ---------------------------------------------------------------------------
// x fp32 -> bf16, 4 elems/thread
// ---------------------------------------------------------------------------
__global__ __launch_bounds__(256) void cvt_x_kernel(
    const float* __restrict__ in, bf16* __restrict__ out) {
  size_t i4 = ((size_t)blockIdx.x * 256 + threadIdx.x) * 4;
  float4 v = *(const float4*)(in + i4);
  ushort4 o;
  o.x = f2bu(v.x); o.y = f2bu(v.y); o.z = f2bu(v.z); o.w = f2bu(v.w);
  *(ushort4*)(out + i4) = o;
}

// ---------------------------------------------------------------------------
// Weight convert+transpose: src[K,N] fp32 -> dst[N,K] bf16. Grid exact K*N/256.
// ---------------------------------------------------------------------------
__global__ __launch_bounds__(256) void cvt_tr_kernel(
    const float* __restrict__ src, bf16* __restrict__ dst, int K, int N) {
  int idx = blockIdx.x * 256 + threadIdx.x;
  int k = idx / N, n = idx - k * N;
  dst[(size_t)n * K + k] = __float2bfloat16(src[idx]);
}

// ---------------------------------------------------------------------------
// srconv im2col base offsets per output token
// ---------------------------------------------------------------------------
__global__ __launch_bounds__(256) void srbase_kernel(int* __restrict__ base) {
  int t = blockIdx.x * 256 + threadIdx.x;
  if (t >= 6272) return;
  int b = t / 196, p = t - b * 196;
  int oy = p / 14, ox = p - oy * 14;
  base[t] = ((b * 56 + oy * 4) * 56 + ox * 4) * 256;
}

// ---------------------------------------------------------------------------
// MFMA GEMM: C[M,N] = A[M,K](bf16,row-major) @ BT[N,K](bf16,row-major)^T + bias
// 128x128 tile, BK=32, 256 threads (4 waves, 2x2 of 64x64), 16x16x32 bf16 MFMA.
// M%128==0, N%128==0, K%32==0.
// ---------------------------------------------------------------------------
template<typename OT>
__global__ __launch_bounds__(256) void gemm_mfma(
    const bf16* __restrict__ A, const bf16* __restrict__ BT,
    const float* __restrict__ bias, OT* __restrict__ C,
    int M, int K, int N) {
  __shared__ uint4 As[128 * 5];   // rows padded to 5 x 16B (40 bf16)
  __shared__ uint4 Bs[128 * 5];
  const int tid = threadIdx.x;
  const int m0 = blockIdx.y * 128;
  const int n0 = blockIdx.x * 128;
  const int wave = tid >> 6, lane = tid & 63;
  const int wm = (wave >> 1) * 64, wn = (wave & 1) * 64;
  const int l15 = lane & 15, quad = lane >> 4;
  floatx4 zero = {0.f, 0.f, 0.f, 0.f};
  floatx4 acc[4][4];
#pragma unroll
  for (int i = 0; i < 4; i++)
#pragma unroll
    for (int j = 0; j < 4; j++) acc[i][j] = zero;

  for (int k0 = 0; k0 < K; k0 += 32) {
#pragma unroll
    for (int it = 0; it < 2; it++) {
      int id = it * 256 + tid;
      int row = id >> 2, seg = id & 3;
      As[row * 5 + seg] = *(const uint4*)(A + (size_t)(m0 + row) * K + k0 + seg * 8);
      Bs[row * 5 + seg] = *(const uint4*)(BT + (size_t)(n0 + row) * K + k0 + seg * 8);
    }
    __syncthreads();
    short8 af[4], bfr[4];
#pragma unroll
    for (int i = 0; i < 4; i++)
      af[i] = *(const short8*)&As[(wm + i * 16 + l15) * 5 + quad];
#pragma unroll
    for (int j = 0; j < 4; j++)
      bfr[j] = *(const short8*)&Bs[(wn + j * 16 + l15) * 5 + quad];
#pragma unroll
    for (int i = 0; i < 4; i++)
#pragma unroll
      for (int j = 0; j < 4; j++)
        acc[i][j] = __builtin_amdgcn_mfma_f32_16x16x32_bf16(af[i], bfr[j], acc[i][j], 0, 0, 0);
    __syncthreads();
  }
#pragma unroll
  for (int j = 0; j < 4; j++) {
    int n = n0 + wn + j * 16 + l15;
    float bv = bias ? bias[n] : 0.0f;
#pragma unroll
    for (int i = 0; i < 4; i++) {
      int m = m0 + wm + i * 16 + quad * 4;
#pragma unroll
      for (int r = 0; r < 4; r++)
        storeT(&C[(size_t)(m + r) * N + n], acc[i][j][r] + bv);
    }
  }
}

// ---------------------------------------------------------------------------
// srconv as MFMA GEMM: M=6272 tokens, K=4096 (16 pix x 256 ch), N=256.
// A staged via im2col: k-chunk of 32 = 32 contiguous channels of one pixel.
// ---------------------------------------------------------------------------
__global__ __launch_bounds__(256) void gemm_sr(
    const bf16* __restrict__ X, const bf16* __restrict__ BT,
    const float* __restrict__ bias, const int* __restrict__ base,
    float* __restrict__ C) {
  __shared__ uint4 As[128 * 5];
  __shared__ uint4 Bs[128 * 5];
  __shared__ int sBase[128];
  const int tid = threadIdx.x;
  const int m0 = blockIdx.y * 128;
  const int n0 = blockIdx.x * 128;
  if (tid < 128) sBase[tid] = base[m0 + tid];
  const int wave = tid >> 6, lane = tid & 63;
  const int wm = (wave >> 1) * 64, wn = (wave & 1) * 64;
  const int l15 = lane & 15, quad = lane >> 4;
  floatx4 zero = {0.f, 0.f, 0.f, 0.f};
  floatx4 acc[4][4];
#pragma unroll
  for (int i = 0; i < 4; i++)
#pragma unroll
    for (int j = 0; j < 4; j++) acc[i][j] = zero;
  __syncthreads();

  for (int k0 = 0; k0 < 4096; k0 += 32) {
#pragma unroll
    for (int it = 0; it < 2; it++) {
      int id = it * 256 + tid;
      int row = id >> 2, seg = id & 3;
      int k = k0 + seg * 8;
      int kp = k >> 8, c = k & 255;
      int off = ((kp >> 2) * 56 + (kp & 3)) * 256 + c;
      As[row * 5 + seg] = *(const uint4*)(X + (size_t)sBase[row] + off);
      Bs[row * 5 + seg] = *(const uint4*)(BT + (size_t)(n0 + row) * 4096 + k);
    }
    __syncthreads();
    short8 af[4], bfr[4];
#pragma unroll
    for (int i = 0; i < 4; i++)
      af[i] = *(const short8*)&As[(wm + i * 16 + l15) * 5 + quad];
#pragma unroll
    for (int j = 0; j < 4; j++)
      bfr[j] = *(const short8*)&Bs[(wn + j * 16 + l15) * 5 + quad];
#pragma unroll
    for (int i = 0; i < 4; i++)
#pragma unroll
      for (int j = 0; j < 4; j++)
        acc[i][j] = __builtin_amdgcn_mfma_f32_16x16x32_bf16(af[i], bfr[j], acc[i][j], 0, 0, 0);
    __syncthreads();
  }
#pragma unroll
  for (int j = 0; j < 4; j++) {
    int n = n0 + wn + j * 16 + l15;
    float bv = bias[n];
#pragma unroll
    for (int i = 0; i < 4; i++) {
      int m = m0 + wm + i * 16 + quad * 4;
#pragma unroll
      for (int r = 0; r < 4; r++)
        C[(size_t)(m + r) * 256 + n] = acc[i][j][r] + bv;
    }
  }
}

// ---------------------------------------------------------------------------
// proj MFMA GEMM with fused A = concat(X1,X2)+L2. M=100352, K=256, N=256.
// ---------------------------------------------------------------------------
__global__ __launch_bounds__(256) void gemm_proj_mfma(
    const bf16* __restrict__ X1, const bf16* __restrict__ X2,
    const bf16* __restrict__ L2, const bf16* __restrict__ BT,
    const float* __restrict__ bias, float* __restrict__ C) {
  __shared__ uint4 As[128 * 5];
  __shared__ uint4 Bs[128 * 5];
  const int tid = threadIdx.x;
  const int m0 = blockIdx.y * 128;
  const int n0 = blockIdx.x * 128;
  const int wave = tid >> 6, lane = tid & 63;
  const int wm = (wave >> 1) * 64, wn = (wave & 1) * 64;
  const int l15 = lane & 15, quad = lane >> 4;
  floatx4 zero = {0.f, 0.f, 0.f, 0.f};
  floatx4 acc[4][4];
#pragma unroll
  for (int i = 0; i < 4; i++)
#pragma unroll
    for (int j = 0; j < 4; j++) acc[i][j] = zero;

  for (int k0 = 0; k0 < 256; k0 += 32) {
#pragma unroll
    for (int it = 0; it < 2; it++) {
      int id = it * 256 + tid;
      int row = id >> 2, seg = id & 3;
      int k = k0 + seg * 8;
      int mrow = m0 + row;
      const bf16* src = (k < 128) ? X1 + (size_t)mrow * 128 + k
                                  : X2 + (size_t)mrow * 128 + (k - 128);
      uint4 va = *(const uint4*)src;
      uint4 vl = *(const uint4*)(L2 + (size_t)mrow * 256 + k);
      const unsigned short* pa = (const unsigned short*)&va;
      const unsigned short* pl = (const unsigned short*)&vl;
      unsigned short ov[8];
#pragma unroll
      for (int e = 0; e < 8; e++) ov[e] = f2bu(b2f(pa[e]) + b2f(pl[e]));
      As[row * 5 + seg] = *(const uint4*)ov;
      Bs[row * 5 + seg] = *(const uint4*)(BT + (size_t)(n0 + row) * 256 + k);
    }
    __syncthreads();
    short8 af[4], bfr[4];
#pragma unroll
    for (int i = 0; i < 4; i++)
      af[i] = *(const short8*)&As[(wm + i * 16 + l15) * 5 + quad];
#pragma unroll
    for (int j = 0; j < 4; j++)
      bfr[j] = *(const short8*)&Bs[(wn + j * 16 + l15) * 5 + quad];
#pragma unroll
    for (int i = 0; i < 4; i++)
#pragma unroll
      for (int j = 0; j < 4; j++)
        acc[i][j] = __builtin_amdgcn_mfma_f32_16x16x32_bf16(af[i], bfr[j], acc[i][j], 0, 0, 0);
    __syncthreads();
  }
#pragma unroll
  for (int j = 0; j < 4; j++) {
    int n = n0 + wn + j * 16 + l15;
    float bv = bias[n];
#pragma unroll
    for (int i = 0; i < 4; i++) {
      int m = m0 + wm + i * 16 + quad * 4;
#pragma unroll
      for (int r = 0; r < 4; r++)
        C[(size_t)(m + r) * 256 + n] = acc[i][j][r] + bv;
    }
  }
}

// ---------------------------------------------------------------------------
// Depthwise 3x3 SAME conv, NHWC, B=32,H=W=56,C=256. One thread per element.
// ---------------------------------------------------------------------------
__global__ __launch_bounds__(256) void dwconv_kernel(
    const bf16* __restrict__ in, const float* __restrict__ w,
    const float* __restrict__ bias, bf16* __restrict__ out) {
  const size_t idx = (size_t)blockIdx.x * 256 + threadIdx.x;
  const int c = (int)(idx & 255);
  const int sp = (int)(idx >> 8);
  const int xx = sp % 56;
  const int yb = sp / 56;
  const int yy = yb % 56;
  const int b  = yb / 56;
  float acc = bias[c];
#pragma unroll
  for (int dy = 0; dy < 3; dy++) {
    int y = yy + dy - 1;
    if ((unsigned)y >= 56u) continue;
#pragma unroll
    for (int dx = 0; dx < 3; dx++) {
      int x = xx + dx - 1;
      if ((unsigned)x >= 56u) continue;
      acc += toF(in[((size_t)((b * 56 + y) * 56 + x)) * 256 + c]) *
             w[(dy * 3 + dx) * 256 + c];
    }
  }
  out[idx] = __float2bfloat16(acc);
}

// ---------------------------------------------------------------------------
// LayerNorm (over C=256) + exact GELU. One block per token. Output bf16.
// ---------------------------------------------------------------------------
__global__ __launch_bounds__(256) void ln_gelu_kernel(
    const float* __restrict__ in, const float* __restrict__ g,
    const float* __restrict__ bb, bf16* __restrict__ out) {
  const int tok = blockIdx.x;
  const int tid = threadIdx.x;
  float v = in[(size_t)tok * 256 + tid];
  float s = v, s2 = v * v;
#pragma unroll
  for (int o = 32; o > 0; o >>= 1) {
    s += __shfl_down(s, o, 64);
    s2 += __shfl_down(s2, o, 64);
  }
  __shared__ float rs[4], rs2[4];
  int wid = tid >> 6, lane = tid & 63;
  if (lane == 0) { rs[wid] = s; rs2[wid] = s2; }
  __syncthreads();
  float tot = rs[0] + rs[1] + rs[2] + rs[3];
  float tot2 = rs2[0] + rs2[1] + rs2[2] + rs2[3];
  float mean = tot * (1.0f / 256.0f);
  float var = tot2 * (1.0f / 256.0f) - mean * mean;
  float y = (v - mean) * rsqrtf(var + 1e-5f) * g[tid] + bb[tid];
  out[(size_t)tok * 256 + tid] =
      __float2bfloat16(0.5f * y * (1.0f + erff(y * 0.70710678118654752f)));
}

// ---------------------------------------------------------------------------
// attn1: global attention vs 196 downsampled kv. One thread = 1 query.
// Single-pass softmax (scores bounded, no max subtraction needed).
// ---------------------------------------------------------------------------
__global__ __launch_bounds__(256) void attn1_kernel(
    const bf16* __restrict__ Q, const float* __restrict__ KV,
    bf16* __restrict__ O) {
  __shared__ float sk[196 * 32];
  __shared__ float sv[196 * 32];
  const int b = blockIdx.z, h = blockIdx.y, chunk = blockIdx.x;
  const int tid = threadIdx.x;
  for (int i = tid; i < 196 * 32; i += 256) {
    int m = i >> 5, dd = i & 31;
    const float* kvp = KV + ((size_t)(b * 196 + m)) * 256 + h * 32 + dd;
    sk[i] = kvp[0];
    sv[i] = kvp[128];
  }
  __syncthreads();
  const int qrow = chunk * 256 + tid;
  if (qrow >= 3136) return;
  float q[32];
  const bf16* qp = Q + ((size_t)(b * 3136 + qrow)) * 128 + h * 32;
#pragma unroll
  for (int dd = 0; dd < 32; dd++) q[dd] = toF(qp[dd]);
  const float scale = 0.17677669529663687f;  // 32^-0.5
  float l = 0.f;
  float acc[32] = {};
  for (int m = 0; m < 196; m++) {
    const float* kp = sk + m * 32;
    float s = 0.f;
#pragma unroll
    for (int dd = 0; dd < 32; dd++) s += q[dd] * kp[dd];
    float p = __expf(s * scale);
    l += p;
    const float* vp = sv + m * 32;
#pragma unroll
    for (int dd = 0; dd < 32; dd++) acc[dd] += p * vp[dd];
  }
  float inv = 1.0f / l;
  bf16* op = O + ((size_t)(b * 3136 + qrow)) * 128 + h * 32;
#pragma unroll
  for (int dd = 0; dd < 32; dd++) op[dd] = __float2bfloat16(acc[dd] * inv);
}

// ---------------------------------------------------------------------------
// attn2: 7x7 window attention. One block (64 thr) per (window, h, b).
// ---------------------------------------------------------------------------
__global__ __launch_bounds__(64) void attn2_kernel(
    const bf16* __restrict__ Q2, const bf16* __restrict__ KV2,
    bf16* __restrict__ O) {
  __shared__ float sk[49 * 32];
  __shared__ float sv[49 * 32];
  const int b = blockIdx.z, h = blockIdx.y, wi = blockIdx.x;
  const int wy = wi >> 3, wx = wi & 7;
  const int tid = threadIdx.x;
  for (int i = tid; i < 49 * 32; i += 64) {
    int m = i >> 5, dd = i & 31;
    int iy = m / 7, ix = m - (m / 7) * 7;
    int n = (wy * 7 + iy) * 56 + wx * 7 + ix;
    const bf16* kvp = KV2 + ((size_t)(b * 3136 + n)) * 256 + h * 32 + dd;
    sk[i] = toF(kvp[0]);
    sv[i] = toF(kvp[128]);
  }
  __syncthreads();
  if (tid >= 49) return;
  const int iy = tid / 7, ix = tid - (tid / 7) * 7;
  const int n = (wy * 7 + iy) * 56 + wx * 7 + ix;
  float q[32];
  const bf16* qp = Q2 + ((size_t)(b * 3136 + n)) * 128 + h * 32;
#pragma unroll
  for (int dd = 0; dd < 32; dd++) q[dd] = toF(qp[dd]);
  const float scale = 0.17677669529663687f;
  float l = 0.f;
  float acc[32] = {};
  for (int m = 0; m < 49; m++) {
    const float* kp = sk + m * 32;
    float s = 0.f;
#pragma unroll
    for (int dd = 0; dd < 32; dd++) s += q[dd] * kp[dd];
    float p = __expf(s * scale);
    l += p;
    const float* vp = sv + m * 32;
#pragma unroll
    for (int dd = 0; dd < 32; dd++) acc[dd] += p * vp[dd];
  }
  float inv = 1.0f / l;
  bf16* op = O + ((size_t)(b * 3136 + n)) * 128 + h * 32;
#pragma unroll
  for (int dd = 0; dd < 32; dd++) op[dd] = __float2bfloat16(acc[dd] * inv);
}

// ---------------------------------------------------------------------------
extern "C" void kernel_launch(void* const* d_in, const int* in_sizes, int n_in,
                              void* d_out, int out_size, void* d_ws, size_t ws_size,
                              hipStream_t stream) {
  const float* x           = (const float*)d_in[0];
  const float* lepe_lin_w  = (const float*)d_in[1];
  const float* lepe_lin_b  = (const float*)d_in[2];
  const float* lepe_conv_w = (const float*)d_in[3];
  const float* lepe_conv_b = (const float*)d_in[4];
  const float* sr_w        = (const float*)d_in[5];
  const float* sr_b        = (const float*)d_in[6];
  const float* norm_g      = (const float*)d_in[7];
  const float* norm_b      = (const float*)d_in[8];
  const float* q1_w        = (const float*)d_in[9];
  const float* kv1_w       = (const float*)d_in[10];
  const float* q2_w        = (const float*)d_in[11];
  const float* kv2_w       = (const float*)d_in[12];
  const float* proj_w      = (const float*)d_in[13];
  const float* proj_b      = (const float*)d_in[14];
  float* out = (float*)d_out;

  // Scratch layout. d_out (102.8 MB fp32) doubles as early scratch:
  //   d_out[0, 51.4M):    xb (bf16 x) — dead after srconv
  //   d_out[51.4, 77.1M): Q2 then Q1 — dead after attn1; proj overwrites all
  // ws (~131 MB):
  //   [0, 51.4M):    L1 (lepe_lin) -> KV2 -> {X1 bf16 @0, X1P @25.7M, X1N @32.1M, KV1 @35.3M}
  //   [51.4, 102.8M): L2 (lepe, persists to proj)
  //   [102.8, 128.5M): X2
  //   [128.5M, ...):  transposed bf16 weights + srbase
  char* ws = (char*)d_ws;
  char* ob = (char*)d_out;
  const size_t szBNC = 100352ull * 256 * 2;   // 51,380,224
  const size_t szBNh = 100352ull * 128 * 2;   // 25,690,112
  bf16*  xb  = (bf16*)ob;
  bf16*  Q2  = (bf16*)(ob + szBNC);
  bf16*  Q1  = Q2;
  bf16*  L1  = (bf16*)ws;
  bf16*  KV2 = (bf16*)ws;
  bf16*  X1  = (bf16*)ws;
  float* X1P = (float*)(ws + 25690112);
  bf16*  X1N = (bf16*)(ws + 32112640);
  float* KV1 = (float*)(ws + 35323904);
  bf16*  L2  = (bf16*)(ws + szBNC);
  bf16*  X2  = (bf16*)(ws + 2 * szBNC);
  char*  wtb = ws + 2 * szBNC + szBNh;
  bf16* wT_lepe = (bf16*)(wtb);
  bf16* wT_q1   = (bf16*)(wtb + 131072);
  bf16* wT_q2   = (bf16*)(wtb + 196608);
  bf16* wT_kv1  = (bf16*)(wtb + 262144);
  bf16* wT_kv2  = (bf16*)(wtb + 393216);
  bf16* wT_proj = (bf16*)(wtb + 524288);
  bf16* wT_sr   = (bf16*)(wtb + 655360);
  int*  srbase  = (int*)(wtb + 655360 + 2097152);

  // 0. conversions
  cvt_x_kernel<<<25088, 256, 0, stream>>>(x, xb);
  cvt_tr_kernel<<<256, 256, 0, stream>>>(lepe_lin_w, wT_lepe, 256, 256);
  cvt_tr_kernel<<<128, 256, 0, stream>>>(q1_w, wT_q1, 256, 128);
  cvt_tr_kernel<<<128, 256, 0, stream>>>(q2_w, wT_q2, 256, 128);
  cvt_tr_kernel<<<256, 256, 0, stream>>>(kv1_w, wT_kv1, 256, 256);
  cvt_tr_kernel<<<256, 256, 0, stream>>>(kv2_w, wT_kv2, 256, 256);
  cvt_tr_kernel<<<256, 256, 0, stream>>>(proj_w, wT_proj, 256, 256);
  cvt_tr_kernel<<<4096, 256, 0, stream>>>(sr_w, wT_sr, 4096, 256);
  srbase_kernel<<<25, 256, 0, stream>>>(srbase);

  // 1-2. lepe linear + depthwise conv
  gemm_mfma<bf16><<<dim3(2, 784), 256, 0, stream>>>(
      xb, wT_lepe, lepe_lin_b, L1, 100352, 256, 256);
  dwconv_kernel<<<100352, 256, 0, stream>>>(L1, lepe_conv_w, lepe_conv_b, L2);

  // 3-5. branch 2 (window attention)
  gemm_mfma<bf16><<<dim3(2, 784), 256, 0, stream>>>(
      xb, wT_kv2, nullptr, KV2, 100352, 256, 256);
  gemm_mfma<bf16><<<dim3(1, 784), 256, 0, stream>>>(
      xb, wT_q2, nullptr, Q2, 100352, 256, 128);
  attn2_kernel<<<dim3(64, 4, 32), 64, 0, stream>>>(Q2, KV2, X2);

  // 6-10. branch 1 (sr-downsampled global attention)
  gemm_mfma<bf16><<<dim3(1, 784), 256, 0, stream>>>(
      xb, wT_q1, nullptr, Q1, 100352, 256, 128);
  gemm_sr<<<dim3(2, 49), 256, 0, stream>>>(xb, wT_sr, sr_b, srbase, X1P);
  ln_gelu_kernel<<<6272, 256, 0, stream>>>(X1P, norm_g, norm_b, X1N);
  gemm_mfma<float><<<dim3(2, 49), 256, 0, stream>>>(
      X1N, wT_kv1, nullptr, KV1, 6272, 256, 256);
  attn1_kernel<<<dim3(13, 4, 32), 256, 0, stream>>>(Q1, KV1, X1);

  // 11. fused concat + lepe add + proj
  gemm_proj_mfma<<<dim3(2, 784), 256, 0, stream>>>(
      X1, X2, L2, wT_proj, proj_b, out);
}

// Round 4
// 646.886 us; speedup vs baseline: 2.9482x; 1.3984x over previous
//
#include <hip/hip_runtime.h>
#include <hip/hip_bf16.h>

typedef __hip_bfloat16 bf16;
typedef __attribute__((ext_vector_type(8))) short short8;
typedef __attribute__((ext_vector_type(4))) float floatx4;

__device__ __forceinline__ float toF(bf16 v){ return __bfloat162float(v); }
__device__ __forceinline__ float b2f(unsigned short u){
  return __uint_as_float(((unsigned int)u) << 16);
}
__device__ __forceinline__ unsigned short f2bu(float f){
  bf16 h = __float2bfloat16(f);
  return *(unsigned short*)&h;
}
__device__ __forceinline__ void storeT(bf16* p, float v){ *p = __float2bfloat16(v); }
__device__ __forceinline__ void storeT(float* p, float v){ *p = v; }

// ---------------------------------------------------------------------------
// x fp32 -> bf16, 4 elems/thread
// ---------------------------------------------------------------------------
__global__ __launch_bounds__(256) void cvt_x_kernel(
    const float* __restrict__ in, bf16* __restrict__ out) {
  size_t i4 = ((size_t)blockIdx.x * 256 + threadIdx.x) * 4;
  float4 v = *(const float4*)(in + i4);
  ushort4 o;
  o.x = f2bu(v.x); o.y = f2bu(v.y); o.z = f2bu(v.z); o.w = f2bu(v.w);
  *(ushort4*)(out + i4) = o;
}

// ---------------------------------------------------------------------------
// Weight convert+transpose: src[K,N] fp32 -> dst[N,K] bf16. Grid exact K*N/256.
// ---------------------------------------------------------------------------
__global__ __launch_bounds__(256) void cvt_tr_kernel(
    const float* __restrict__ src, bf16* __restrict__ dst, int K, int N) {
  int idx = blockIdx.x * 256 + threadIdx.x;
  int k = idx / N, n = idx - k * N;
  dst[(size_t)n * K + k] = __float2bfloat16(src[idx]);
}

// ---------------------------------------------------------------------------
// srconv im2col base offsets per output token
// ---------------------------------------------------------------------------
__global__ __launch_bounds__(256) void srbase_kernel(int* __restrict__ base) {
  int t = blockIdx.x * 256 + threadIdx.x;
  if (t >= 6272) return;
  int b = t / 196, p = t - b * 196;
  int oy = p / 14, ox = p - oy * 14;
  base[t] = ((b * 56 + oy * 4) * 56 + ox * 4) * 256;
}

// ---------------------------------------------------------------------------
// MFMA GEMM: C[M,N] = A[M,K](bf16,row-major) @ BT[N,K](bf16,row-major)^T + bias
// 128x128 tile, BK=32, 256 threads (4 waves, 2x2 of 64x64), 16x16x32 bf16 MFMA.
// ---------------------------------------------------------------------------
template<typename OT>
__global__ __launch_bounds__(256) void gemm_mfma(
    const bf16* __restrict__ A, const bf16* __restrict__ BT,
    const float* __restrict__ bias, OT* __restrict__ C,
    int M, int K, int N) {
  __shared__ uint4 As[128 * 5];   // rows padded to 5 x 16B (40 bf16)
  __shared__ uint4 Bs[128 * 5];
  const int tid = threadIdx.x;
  const int m0 = blockIdx.y * 128;
  const int n0 = blockIdx.x * 128;
  const int wave = tid >> 6, lane = tid & 63;
  const int wm = (wave >> 1) * 64, wn = (wave & 1) * 64;
  const int l15 = lane & 15, quad = lane >> 4;
  floatx4 zero = {0.f, 0.f, 0.f, 0.f};
  floatx4 acc[4][4];
#pragma unroll
  for (int i = 0; i < 4; i++)
#pragma unroll
    for (int j = 0; j < 4; j++) acc[i][j] = zero;

  for (int k0 = 0; k0 < K; k0 += 32) {
#pragma unroll
    for (int it = 0; it < 2; it++) {
      int id = it * 256 + tid;
      int row = id >> 2, seg = id & 3;
      As[row * 5 + seg] = *(const uint4*)(A + (size_t)(m0 + row) * K + k0 + seg * 8);
      Bs[row * 5 + seg] = *(const uint4*)(BT + (size_t)(n0 + row) * K + k0 + seg * 8);
    }
    __syncthreads();
    short8 af[4], bfr[4];
#pragma unroll
    for (int i = 0; i < 4; i++)
      af[i] = *(const short8*)&As[(wm + i * 16 + l15) * 5 + quad];
#pragma unroll
    for (int j = 0; j < 4; j++)
      bfr[j] = *(const short8*)&Bs[(wn + j * 16 + l15) * 5 + quad];
#pragma unroll
    for (int i = 0; i < 4; i++)
#pragma unroll
      for (int j = 0; j < 4; j++)
        acc[i][j] = __builtin_amdgcn_mfma_f32_16x16x32_bf16(af[i], bfr[j], acc[i][j], 0, 0, 0);
    __syncthreads();
  }
#pragma unroll
  for (int j = 0; j < 4; j++) {
    int n = n0 + wn + j * 16 + l15;
    float bv = bias ? bias[n] : 0.0f;
#pragma unroll
    for (int i = 0; i < 4; i++) {
      int m = m0 + wm + i * 16 + quad * 4;
#pragma unroll
      for (int r = 0; r < 4; r++)
        storeT(&C[(size_t)(m + r) * N + n], acc[i][j][r] + bv);
    }
  }
}

// ---------------------------------------------------------------------------
// srconv as MFMA GEMM: M=6272 tokens, K=4096 (16 pix x 256 ch), N=256.
// ---------------------------------------------------------------------------
__global__ __launch_bounds__(256) void gemm_sr(
    const bf16* __restrict__ X, const bf16* __restrict__ BT,
    const float* __restrict__ bias, const int* __restrict__ base,
    float* __restrict__ C) {
  __shared__ uint4 As[128 * 5];
  __shared__ uint4 Bs[128 * 5];
  __shared__ int sBase[128];
  const int tid = threadIdx.x;
  const int m0 = blockIdx.y * 128;
  const int n0 = blockIdx.x * 128;
  if (tid < 128) sBase[tid] = base[m0 + tid];
  const int wave = tid >> 6, lane = tid & 63;
  const int wm = (wave >> 1) * 64, wn = (wave & 1) * 64;
  const int l15 = lane & 15, quad = lane >> 4;
  floatx4 zero = {0.f, 0.f, 0.f, 0.f};
  floatx4 acc[4][4];
#pragma unroll
  for (int i = 0; i < 4; i++)
#pragma unroll
    for (int j = 0; j < 4; j++) acc[i][j] = zero;
  __syncthreads();

  for (int k0 = 0; k0 < 4096; k0 += 32) {
#pragma unroll
    for (int it = 0; it < 2; it++) {
      int id = it * 256 + tid;
      int row = id >> 2, seg = id & 3;
      int k = k0 + seg * 8;
      int kp = k >> 8, c = k & 255;
      int off = ((kp >> 2) * 56 + (kp & 3)) * 256 + c;
      As[row * 5 + seg] = *(const uint4*)(X + (size_t)sBase[row] + off);
      Bs[row * 5 + seg] = *(const uint4*)(BT + (size_t)(n0 + row) * 4096 + k);
    }
    __syncthreads();
    short8 af[4], bfr[4];
#pragma unroll
    for (int i = 0; i < 4; i++)
      af[i] = *(const short8*)&As[(wm + i * 16 + l15) * 5 + quad];
#pragma unroll
    for (int j = 0; j < 4; j++)
      bfr[j] = *(const short8*)&Bs[(wn + j * 16 + l15) * 5 + quad];
#pragma unroll
    for (int i = 0; i < 4; i++)
#pragma unroll
      for (int j = 0; j < 4; j++)
        acc[i][j] = __builtin_amdgcn_mfma_f32_16x16x32_bf16(af[i], bfr[j], acc[i][j], 0, 0, 0);
    __syncthreads();
  }
#pragma unroll
  for (int j = 0; j < 4; j++) {
    int n = n0 + wn + j * 16 + l15;
    float bv = bias[n];
#pragma unroll
    for (int i = 0; i < 4; i++) {
      int m = m0 + wm + i * 16 + quad * 4;
#pragma unroll
      for (int r = 0; r < 4; r++)
        C[(size_t)(m + r) * 256 + n] = acc[i][j][r] + bv;
    }
  }
}

// ---------------------------------------------------------------------------
// proj MFMA GEMM with fused A = concat(X1,X2)+L2. M=100352, K=256, N=256.
// ---------------------------------------------------------------------------
__global__ __launch_bounds__(256) void gemm_proj_mfma(
    const bf16* __restrict__ X1, const bf16* __restrict__ X2,
    const bf16* __restrict__ L2, const bf16* __restrict__ BT,
    const float* __restrict__ bias, float* __restrict__ C) {
  __shared__ uint4 As[128 * 5];
  __shared__ uint4 Bs[128 * 5];
  const int tid = threadIdx.x;
  const int m0 = blockIdx.y * 128;
  const int n0 = blockIdx.x * 128;
  const int wave = tid >> 6, lane = tid & 63;
  const int wm = (wave >> 1) * 64, wn = (wave & 1) * 64;
  const int l15 = lane & 15, quad = lane >> 4;
  floatx4 zero = {0.f, 0.f, 0.f, 0.f};
  floatx4 acc[4][4];
#pragma unroll
  for (int i = 0; i < 4; i++)
#pragma unroll
    for (int j = 0; j < 4; j++) acc[i][j] = zero;

  for (int k0 = 0; k0 < 256; k0 += 32) {
#pragma unroll
    for (int it = 0; it < 2; it++) {
      int id = it * 256 + tid;
      int row = id >> 2, seg = id & 3;
      int k = k0 + seg * 8;
      int mrow = m0 + row;
      const bf16* src = (k < 128) ? X1 + (size_t)mrow * 128 + k
                                  : X2 + (size_t)mrow * 128 + (k - 128);
      uint4 va = *(const uint4*)src;
      uint4 vl = *(const uint4*)(L2 + (size_t)mrow * 256 + k);
      const unsigned short* pa = (const unsigned short*)&va;
      const unsigned short* pl = (const unsigned short*)&vl;
      unsigned short ov[8];
#pragma unroll
      for (int e = 0; e < 8; e++) ov[e] = f2bu(b2f(pa[e]) + b2f(pl[e]));
      As[row * 5 + seg] = *(const uint4*)ov;
      Bs[row * 5 + seg] = *(const uint4*)(BT + (size_t)(n0 + row) * 256 + k);
    }
    __syncthreads();
    short8 af[4], bfr[4];
#pragma unroll
    for (int i = 0; i < 4; i++)
      af[i] = *(const short8*)&As[(wm + i * 16 + l15) * 5 + quad];
#pragma unroll
    for (int j = 0; j < 4; j++)
      bfr[j] = *(const short8*)&Bs[(wn + j * 16 + l15) * 5 + quad];
#pragma unroll
    for (int i = 0; i < 4; i++)
#pragma unroll
      for (int j = 0; j < 4; j++)
        acc[i][j] = __builtin_amdgcn_mfma_f32_16x16x32_bf16(af[i], bfr[j], acc[i][j], 0, 0, 0);
    __syncthreads();
  }
#pragma unroll
  for (int j = 0; j < 4; j++) {
    int n = n0 + wn + j * 16 + l15;
    float bv = bias[n];
#pragma unroll
    for (int i = 0; i < 4; i++) {
      int m = m0 + wm + i * 16 + quad * 4;
#pragma unroll
      for (int r = 0; r < 4; r++)
        C[(size_t)(m + r) * 256 + n] = acc[i][j][r] + bv;
    }
  }
}

// ---------------------------------------------------------------------------
// Depthwise 3x3 SAME conv, vectorized: one thread = 8 channels of one pixel.
// ---------------------------------------------------------------------------
__global__ __launch_bounds__(256) void dwconv8_kernel(
    const bf16* __restrict__ in, const float* __restrict__ w,
    const float* __restrict__ bias, bf16* __restrict__ out) {
  const int idx = blockIdx.x * 256 + threadIdx.x;   // 3,211,264 total
  const int c8 = (idx & 31) * 8;
  const int sp = idx >> 5;
  const int xx = sp % 56;
  const int yb = sp / 56;
  const int yy = yb % 56;
  const int b  = yb / 56;
  float4 bb0 = *(const float4*)&bias[c8];
  float4 bb1 = *(const float4*)&bias[c8 + 4];
  float acc[8] = {bb0.x, bb0.y, bb0.z, bb0.w, bb1.x, bb1.y, bb1.z, bb1.w};
#pragma unroll
  for (int dy = 0; dy < 3; dy++) {
    int y = yy + dy - 1;
    if ((unsigned)y >= 56u) continue;
#pragma unroll
    for (int dx = 0; dx < 3; dx++) {
      int x = xx + dx - 1;
      if ((unsigned)x >= 56u) continue;
      uint4 v = *(const uint4*)&in[((size_t)((b * 56 + y) * 56 + x)) * 256 + c8];
      const unsigned short* pv = (const unsigned short*)&v;
      float4 w0 = *(const float4*)&w[(dy * 3 + dx) * 256 + c8];
      float4 w1 = *(const float4*)&w[(dy * 3 + dx) * 256 + c8 + 4];
      float wf[8] = {w0.x, w0.y, w0.z, w0.w, w1.x, w1.y, w1.z, w1.w};
#pragma unroll
      for (int e = 0; e < 8; e++) acc[e] += b2f(pv[e]) * wf[e];
    }
  }
  unsigned short o[8];
#pragma unroll
  for (int e = 0; e < 8; e++) o[e] = f2bu(acc[e]);
  *(uint4*)&out[(size_t)sp * 256 + c8] = *(const uint4*)o;
}

// ---------------------------------------------------------------------------
// LayerNorm (over C=256) + exact GELU. One block per token. Output bf16.
// ---------------------------------------------------------------------------
__global__ __launch_bounds__(256) void ln_gelu_kernel(
    const float* __restrict__ in, const float* __restrict__ g,
    const float* __restrict__ bb, bf16* __restrict__ out) {
  const int tok = blockIdx.x;
  const int tid = threadIdx.x;
  float v = in[(size_t)tok * 256 + tid];
  float s = v, s2 = v * v;
#pragma unroll
  for (int o = 32; o > 0; o >>= 1) {
    s += __shfl_down(s, o, 64);
    s2 += __shfl_down(s2, o, 64);
  }
  __shared__ float rs[4], rs2[4];
  int wid = tid >> 6, lane = tid & 63;
  if (lane == 0) { rs[wid] = s; rs2[wid] = s2; }
  __syncthreads();
  float tot = rs[0] + rs[1] + rs[2] + rs[3];
  float tot2 = rs2[0] + rs2[1] + rs2[2] + rs2[3];
  float mean = tot * (1.0f / 256.0f);
  float var = tot2 * (1.0f / 256.0f) - mean * mean;
  float y = (v - mean) * rsqrtf(var + 1e-5f) * g[tid] + bb[tid];
  out[(size_t)tok * 256 + tid] =
      __float2bfloat16(0.5f * y * (1.0f + erff(y * 0.70710678118654752f)));
}

// ---------------------------------------------------------------------------
// attn1 (MFMA): per block 256 queries x one (b,h); kv = 196 (padded 224).
// No-max softmax -> l and O accumulate across kv chunks with no rescaling.
// P round-trips through per-wave LDS (C-layout -> A-layout).
// ---------------------------------------------------------------------------
__global__ __launch_bounds__(256) void attn1_mfma(
    const bf16* __restrict__ Q12, const float* __restrict__ KV,
    bf16* __restrict__ O) {
  __shared__ bf16 sk[224 * 32];     // [kv][d]
  __shared__ bf16 svT[32 * 232];    // [d][kv], stride 232 (16B-aligned rows)
  __shared__ bf16 pbuf[4][64 * 32]; // per-wave P [qrow][kv]
  const int b = blockIdx.z, h = blockIdx.y, chunk = blockIdx.x;
  const int tid = threadIdx.x;
  const int wave = tid >> 6, lane = tid & 63;
  const int l15 = lane & 15, quad = lane >> 4;
  for (int i = tid; i < 224 * 32; i += 256) {
    int m = i >> 5, dd = i & 31;
    float kf = 0.f, vf = 0.f;
    if (m < 196) {
      const float* p = KV + ((size_t)(b * 196 + m)) * 256 + h * 32 + dd;
      kf = p[0]; vf = p[128];
    }
    sk[m * 32 + dd] = __float2bfloat16(kf);
    svT[dd * 232 + m] = __float2bfloat16(vf);
  }
  __syncthreads();
  const int q0 = chunk * 256 + wave * 64;
  short8 aq[4];
#pragma unroll
  for (int i = 0; i < 4; i++) {
    int qr = q0 + i * 16 + l15; if (qr > 3135) qr = 3135;
    aq[i] = *(const short8*)(Q12 + ((size_t)(b * 3136 + qr)) * 256 + h * 32 + quad * 8);
  }
  const float scale = 0.17677669529663687f;
  floatx4 zero = {0.f, 0.f, 0.f, 0.f};
  floatx4 acc[4][2];
  float lsum[4][4];
#pragma unroll
  for (int i = 0; i < 4; i++) {
    acc[i][0] = zero; acc[i][1] = zero;
#pragma unroll
    for (int r = 0; r < 4; r++) lsum[i][r] = 0.f;
  }
  bf16* pw = pbuf[wave];
  for (int c = 0; c < 7; c++) {
    const int kv0 = c * 32;
    short8 bk[2];
#pragma unroll
    for (int n = 0; n < 2; n++)
      bk[n] = *(const short8*)&sk[(kv0 + n * 16 + l15) * 32 + quad * 8];
    floatx4 s[4][2];
#pragma unroll
    for (int i = 0; i < 4; i++)
#pragma unroll
      for (int n = 0; n < 2; n++)
        s[i][n] = __builtin_amdgcn_mfma_f32_16x16x32_bf16(aq[i], bk[n], zero, 0, 0, 0);
#pragma unroll
    for (int i = 0; i < 4; i++)
#pragma unroll
      for (int n = 0; n < 2; n++) {
        bool valid = (kv0 + n * 16 + l15) < 196;
#pragma unroll
        for (int r = 0; r < 4; r++) {
          float p = valid ? __expf(s[i][n][r] * scale) : 0.f;
          lsum[i][r] += p;
          pw[(i * 16 + quad * 4 + r) * 32 + n * 16 + l15] = __float2bfloat16(p);
        }
      }
    asm volatile("s_waitcnt lgkmcnt(0)" ::: "memory");
    short8 ap[4], bv[2];
#pragma unroll
    for (int i = 0; i < 4; i++)
      ap[i] = *(const short8*)&pw[(i * 16 + l15) * 32 + quad * 8];
#pragma unroll
    for (int n = 0; n < 2; n++)
      bv[n] = *(const short8*)&svT[(n * 16 + l15) * 232 + kv0 + quad * 8];
#pragma unroll
    for (int i = 0; i < 4; i++)
#pragma unroll
      for (int n = 0; n < 2; n++)
        acc[i][n] = __builtin_amdgcn_mfma_f32_16x16x32_bf16(ap[i], bv[n], acc[i][n], 0, 0, 0);
  }
#pragma unroll
  for (int i = 0; i < 4; i++)
#pragma unroll
    for (int r = 0; r < 4; r++) {
      float v = lsum[i][r];
      v += __shfl_xor(v, 1, 64);
      v += __shfl_xor(v, 2, 64);
      v += __shfl_xor(v, 4, 64);
      v += __shfl_xor(v, 8, 64);
      lsum[i][r] = 1.0f / v;
    }
#pragma unroll
  for (int i = 0; i < 4; i++)
#pragma unroll
    for (int r = 0; r < 4; r++) {
      int qr = q0 + i * 16 + quad * 4 + r;
      if (qr < 3136) {
        bf16* op = O + ((size_t)(b * 3136 + qr)) * 128 + h * 32;
        op[l15]      = __float2bfloat16(acc[i][0][r] * lsum[i][r]);
        op[16 + l15] = __float2bfloat16(acc[i][1][r] * lsum[i][r]);
      }
    }
}

// ---------------------------------------------------------------------------
// attn2 (MFMA): one wave per 7x7 window (49 padded to 64). Block = 4 windows.
// Grid (16, 4, 32).
// ---------------------------------------------------------------------------
__global__ __launch_bounds__(256) void attn2_mfma(
    const bf16* __restrict__ Q12, const bf16* __restrict__ KV2,
    bf16* __restrict__ O) {
  __shared__ bf16 sk2[4][64 * 32];   // [win][kv][d]
  __shared__ bf16 svT2[4][32 * 72];  // [win][d][kv], stride 72
  __shared__ bf16 pb2[4][64 * 72];   // per-wave P [qrow][kv], stride 72
  const int b = blockIdx.z, h = blockIdx.y;
  const int tid = threadIdx.x;
  const int wave = tid >> 6, lane = tid & 63;
  const int l15 = lane & 15, quad = lane >> 4;
  for (int i = tid; i < 4 * 2048; i += 256) {
    int wloc = i >> 11, rem = i & 2047;
    int m = rem >> 5, dd = rem & 31;
    int win = blockIdx.x * 4 + wloc;
    int wy = win >> 3, wx = win & 7;
    float kf = 0.f, vf = 0.f;
    if (m < 49) {
      int iy = m / 7, ix = m - (m / 7) * 7;
      int n = (wy * 7 + iy) * 56 + wx * 7 + ix;
      const bf16* p = KV2 + ((size_t)(b * 3136 + n)) * 256 + h * 32 + dd;
      kf = toF(p[0]); vf = toF(p[128]);
    }
    sk2[wloc][m * 32 + dd] = __float2bfloat16(kf);
    svT2[wloc][dd * 72 + m] = __float2bfloat16(vf);
  }
  __syncthreads();
  const int win = blockIdx.x * 4 + wave;
  const int wy = win >> 3, wx = win & 7;
  short8 aq[4];
#pragma unroll
  for (int i = 0; i < 4; i++) {
    int lq = i * 16 + l15; if (lq > 48) lq = 48;
    int iy = lq / 7, ix = lq - (lq / 7) * 7;
    int n = (wy * 7 + iy) * 56 + wx * 7 + ix;
    aq[i] = *(const short8*)(Q12 + ((size_t)(b * 3136 + n)) * 256 + 128 + h * 32 + quad * 8);
  }
  const float scale = 0.17677669529663687f;
  floatx4 zero = {0.f, 0.f, 0.f, 0.f};
  floatx4 acc[4][2];
  float lsum[4][4];
#pragma unroll
  for (int i = 0; i < 4; i++) {
    acc[i][0] = zero; acc[i][1] = zero;
#pragma unroll
    for (int r = 0; r < 4; r++) lsum[i][r] = 0.f;
  }
  bf16* pw = pb2[wave];
  const bf16* skw = sk2[wave];
  const bf16* svw = svT2[wave];
#pragma unroll
  for (int c = 0; c < 2; c++) {
    const int kv0 = c * 32;
    short8 bk[2];
#pragma unroll
    for (int n = 0; n < 2; n++)
      bk[n] = *(const short8*)&skw[(kv0 + n * 16 + l15) * 32 + quad * 8];
    floatx4 s[4][2];
#pragma unroll
    for (int i = 0; i < 4; i++)
#pragma unroll
      for (int n = 0; n < 2; n++)
        s[i][n] = __builtin_amdgcn_mfma_f32_16x16x32_bf16(aq[i], bk[n], zero, 0, 0, 0);
#pragma unroll
    for (int i = 0; i < 4; i++)
#pragma unroll
      for (int n = 0; n < 2; n++) {
        bool valid = (kv0 + n * 16 + l15) < 49;
#pragma unroll
        for (int r = 0; r < 4; r++) {
          float p = valid ? __expf(s[i][n][r] * scale) : 0.f;
          lsum[i][r] += p;
          pw[(i * 16 + quad * 4 + r) * 72 + kv0 + n * 16 + l15] = __float2bfloat16(p);
        }
      }
  }
  asm volatile("s_waitcnt lgkmcnt(0)" ::: "memory");
#pragma unroll
  for (int ks = 0; ks < 2; ks++) {
    short8 ap[4], bv[2];
#pragma unroll
    for (int i = 0; i < 4; i++)
      ap[i] = *(const short8*)&pw[(i * 16 + l15) * 72 + ks * 32 + quad * 8];
#pragma unroll
    for (int n = 0; n < 2; n++)
      bv[n] = *(const short8*)&svw[(n * 16 + l15) * 72 + ks * 32 + quad * 8];
#pragma unroll
    for (int i = 0; i < 4; i++)
#pragma unroll
      for (int n = 0; n < 2; n++)
        acc[i][n] = __builtin_amdgcn_mfma_f32_16x16x32_bf16(ap[i], bv[n], acc[i][n], 0, 0, 0);
  }
#pragma unroll
  for (int i = 0; i < 4; i++)
#pragma unroll
    for (int r = 0; r < 4; r++) {
      float v = lsum[i][r];
      v += __shfl_xor(v, 1, 64);
      v += __shfl_xor(v, 2, 64);
      v += __shfl_xor(v, 4, 64);
      v += __shfl_xor(v, 8, 64);
      lsum[i][r] = 1.0f / v;
    }
#pragma unroll
  for (int i = 0; i < 4; i++)
#pragma unroll
    for (int r = 0; r < 4; r++) {
      int lq = i * 16 + quad * 4 + r;
      if (lq < 49) {
        int iy = lq / 7, ix = lq - (lq / 7) * 7;
        int n = (wy * 7 + iy) * 56 + wx * 7 + ix;
        bf16* op = O + ((size_t)(b * 3136 + n)) * 128 + h * 32;
        op[l15]      = __float2bfloat16(acc[i][0][r] * lsum[i][r]);
        op[16 + l15] = __float2bfloat16(acc[i][1][r] * lsum[i][r]);
      }
    }
}

// ---------------------------------------------------------------------------
extern "C" void kernel_launch(void* const* d_in, const int* in_sizes, int n_in,
                              void* d_out, int out_size, void* d_ws, size_t ws_size,
                              hipStream_t stream) {
  const float* x           = (const float*)d_in[0];
  const float* lepe_lin_w  = (const float*)d_in[1];
  const float* lepe_lin_b  = (const float*)d_in[2];
  const float* lepe_conv_w = (const float*)d_in[3];
  const float* lepe_conv_b = (const float*)d_in[4];
  const float* sr_w        = (const float*)d_in[5];
  const float* sr_b        = (const float*)d_in[6];
  const float* norm_g      = (const float*)d_in[7];
  const float* norm_b      = (const float*)d_in[8];
  const float* q1_w        = (const float*)d_in[9];
  const float* kv1_w       = (const float*)d_in[10];
  const float* q2_w        = (const float*)d_in[11];
  const float* kv2_w       = (const float*)d_in[12];
  const float* proj_w      = (const float*)d_in[13];
  const float* proj_b      = (const float*)d_in[14];
  float* out = (float*)d_out;

  // d_out doubles as early scratch: xb [0,51.4M), Q12 [51.4,102.8M).
  // ws: [0,51.4M) L1 -> KV2 -> {X1P@0, X1N@6.5M, KV1@9.8M, X1@16.3M}
  //     [51.4,102.8M) L2 ; [102.8,128.5M) X2 ; [128.5M..) weightsT + srbase
  char* ws = (char*)d_ws;
  char* ob = (char*)d_out;
  const size_t szBNC = 100352ull * 256 * 2;   // 51,380,224
  const size_t szBNh = 100352ull * 128 * 2;   // 25,690,112
  bf16*  xb  = (bf16*)ob;
  bf16*  Q12 = (bf16*)(ob + szBNC);
  bf16*  L1  = (bf16*)ws;
  bf16*  KV2 = (bf16*)ws;
  float* X1P = (float*)ws;
  bf16*  X1N = (bf16*)(ws + 6815744);
  float* KV1 = (float*)(ws + 10485760);
  bf16*  X1  = (bf16*)(ws + 17825792);
  bf16*  L2  = (bf16*)(ws + szBNC);
  bf16*  X2  = (bf16*)(ws + 2 * szBNC);
  char*  wtb = ws + 2 * szBNC + szBNh;
  bf16* wT_lepe = (bf16*)(wtb);
  bf16* wT_q12  = (bf16*)(wtb + 131072);
  bf16* wT_kv1  = (bf16*)(wtb + 262144);
  bf16* wT_kv2  = (bf16*)(wtb + 393216);
  bf16* wT_proj = (bf16*)(wtb + 524288);
  bf16* wT_sr   = (bf16*)(wtb + 655360);
  int*  srbase  = (int*)(wtb + 655360 + 2097152);

  // 0. conversions
  cvt_x_kernel<<<25088, 256, 0, stream>>>(x, xb);
  cvt_tr_kernel<<<256, 256, 0, stream>>>(lepe_lin_w, wT_lepe, 256, 256);
  cvt_tr_kernel<<<128, 256, 0, stream>>>(q1_w, wT_q12, 256, 128);
  cvt_tr_kernel<<<128, 256, 0, stream>>>(q2_w, wT_q12 + 128 * 256, 256, 128);
  cvt_tr_kernel<<<256, 256, 0, stream>>>(kv1_w, wT_kv1, 256, 256);
  cvt_tr_kernel<<<256, 256, 0, stream>>>(kv2_w, wT_kv2, 256, 256);
  cvt_tr_kernel<<<256, 256, 0, stream>>>(proj_w, wT_proj, 256, 256);
  cvt_tr_kernel<<<4096, 256, 0, stream>>>(sr_w, wT_sr, 4096, 256);
  srbase_kernel<<<25, 256, 0, stream>>>(srbase);

  // 1-2. lepe linear + depthwise conv
  gemm_mfma<bf16><<<dim3(2, 784), 256, 0, stream>>>(
      xb, wT_lepe, lepe_lin_b, L1, 100352, 256, 256);
  dwconv8_kernel<<<12544, 256, 0, stream>>>(L1, lepe_conv_w, lepe_conv_b, L2);

  // 3-4. shared projections
  gemm_mfma<bf16><<<dim3(2, 784), 256, 0, stream>>>(
      xb, wT_kv2, nullptr, KV2, 100352, 256, 256);
  gemm_mfma<bf16><<<dim3(2, 784), 256, 0, stream>>>(
      xb, wT_q12, nullptr, Q12, 100352, 256, 256);

  // 5. window attention (branch 2)
  attn2_mfma<<<dim3(16, 4, 32), 256, 0, stream>>>(Q12, KV2, X2);

  // 6-10. branch 1
  gemm_sr<<<dim3(2, 49), 256, 0, stream>>>(xb, wT_sr, sr_b, srbase, X1P);
  ln_gelu_kernel<<<6272, 256, 0, stream>>>(X1P, norm_g, norm_b, X1N);
  gemm_mfma<float><<<dim3(2, 49), 256, 0, stream>>>(
      X1N, wT_kv1, nullptr, KV1, 6272, 256, 256);
  attn1_mfma<<<dim3(13, 4, 32), 256, 0, stream>>>(Q12, KV1, X1);

  // 11. fused concat + lepe add + proj
  gemm_proj_mfma<<<dim3(2, 784), 256, 0, stream>>>(
      X1, X2, L2, wT_proj, proj_b, out);
}